// Round 1
// baseline (3067.154 us; speedup 1.0000x reference)
//
#include <hip/hip_runtime.h>
#include <math.h>

#define CDIM 256
#define KDIM 1024
#define TOPK 8
#define RPB 32          // rows per block
#define KCH 64          // k-chunk per outer iteration
#define XSS 260         // xs LDS stride (floats), 16B-aligned rows
#define LGS 68          // logit/dist LDS stride (floats), 16B-aligned rows
#define NROWS 65536
#define NELEM 16777216  // B*C*H*W

// ---------------------------------------------------------------- dict norms
__global__ void dl_norms(const float* __restrict__ dict, float* __restrict__ dn) {
    int k = blockIdx.x * 256 + threadIdx.x;
    if (k >= KDIM) return;
    const float* dp = dict + (size_t)k * CDIM;
    float s = 0.f;
    for (int c = 0; c < CDIM; c += 4) {
        float4 v = *(const float4*)(dp + c);
        s += v.x * v.x; s += v.y * v.y; s += v.z * v.z; s += v.w * v.w;
    }
    dn[k] = s;
}

// ---------------------------------------------------------------- main fused
__global__ __launch_bounds__(256, 2)
void dl_main(const float* __restrict__ x, const float* __restrict__ dict,
             const float* __restrict__ Wm, const float* __restrict__ bv,
             const float* __restrict__ dn, float* __restrict__ out,
             float* __restrict__ loss_acc, float* __restrict__ reg_acc,
             int* __restrict__ counts)
{
    __shared__ float xs[RPB][XSS];
    __shared__ float lg_s[RPB][LGS];
    __shared__ float dd_s[RPB][LGS];
    __shared__ float sel_p[RPB][TOPK];
    __shared__ int   sel_i[RPB][TOPK];

    const int t = threadIdx.x;
    const int n0 = blockIdx.x * RPB;
    // x_flat[n][c] = x[b][c][h][w], n = b*4096 + h*64 + w
    const float* xb = x + ((size_t)(n0 >> 12) << 20) + (n0 & 4095);

    // stage 32 rows of x_flat into LDS: xs[r][c]
    {
        int r = t & 31, cp = t >> 5;
        #pragma unroll
        for (int p = 0; p < 32; ++p) {
            int c = p * 8 + cp;
            xs[r][c] = xb[(size_t)c * 4096 + r];
        }
    }
    __syncthreads();

    // per-row ||x||^2 (row-owner threads)
    float xn = 0.f;
    if (t < RPB) {
        for (int c = 0; c < CDIM; c += 4) {
            float4 v = *(const float4*)&xs[t][c];
            xn += v.x * v.x; xn += v.y * v.y; xn += v.z * v.z; xn += v.w * v.w;
        }
    }

    // per-row online softmax state + top-8 (smallest dist) heap, row-owner regs
    float m_run = -INFINITY, s_run = 0.f;
    float hd[TOPK], hl[TOPK]; int hi[TOPK];
    #pragma unroll
    for (int j = 0; j < TOPK; ++j) { hd[j] = INFINITY; hl[j] = 0.f; hi[j] = 0; }

    const int rg = t & 15, kg = t >> 4;   // 16 row-groups x 16 k-groups
    const int r0 = rg * 2;

    for (int kk = 0; kk < KDIM; kk += KCH) {
        const int kb = kk + kg * 4;
        float aW[2][4] = {{0.f,0.f,0.f,0.f},{0.f,0.f,0.f,0.f}};
        float aD[2][4] = {{0.f,0.f,0.f,0.f},{0.f,0.f,0.f,0.f}};
        const float* Wp = Wm   + (size_t)kb * CDIM;
        const float* Dp = dict + (size_t)kb * CDIM;
        for (int c = 0; c < CDIM; c += 4) {
            float4 a0 = *(const float4*)&xs[r0][c];
            float4 a1 = *(const float4*)&xs[r0 + 1][c];
            #pragma unroll
            for (int j = 0; j < 4; ++j) {
                float4 w = *(const float4*)(Wp + (size_t)j * CDIM + c);
                aW[0][j] += a0.x * w.x; aW[0][j] += a0.y * w.y;
                aW[0][j] += a0.z * w.z; aW[0][j] += a0.w * w.w;
                aW[1][j] += a1.x * w.x; aW[1][j] += a1.y * w.y;
                aW[1][j] += a1.z * w.z; aW[1][j] += a1.w * w.w;
                float4 d = *(const float4*)(Dp + (size_t)j * CDIM + c);
                aD[0][j] += a0.x * d.x; aD[0][j] += a0.y * d.y;
                aD[0][j] += a0.z * d.z; aD[0][j] += a0.w * d.w;
                aD[1][j] += a1.x * d.x; aD[1][j] += a1.y * d.y;
                aD[1][j] += a1.z * d.z; aD[1][j] += a1.w * d.w;
            }
        }
        #pragma unroll
        for (int j = 0; j < 4; ++j) {
            float bk = bv[kb + j];
            float dk = dn[kb + j];
            lg_s[r0][kg * 4 + j]     = aW[0][j] + bk;
            lg_s[r0 + 1][kg * 4 + j] = aW[1][j] + bk;
            dd_s[r0][kg * 4 + j]     = dk - 2.f * aD[0][j];
            dd_s[r0 + 1][kg * 4 + j] = dk - 2.f * aD[1][j];
        }
        __syncthreads();
        if (t < RPB) {
            // online softmax over this chunk
            float mx = m_run;
            for (int j = 0; j < KCH; ++j) mx = fmaxf(mx, lg_s[t][j]);
            float s = s_run * __expf(m_run - mx);
            for (int j = 0; j < KCH; ++j) s += __expf(lg_s[t][j] - mx);
            m_run = mx; s_run = s;
            // top-8 smallest dist, stable (earlier index wins ties)
            for (int j = 0; j < KCH; ++j) {
                float dv = xn + dd_s[t][j];
                if (dv < hd[TOPK - 1]) {
                    float cd = dv, cl = lg_s[t][j]; int ci = kk + j;
                    #pragma unroll
                    for (int p = 0; p < TOPK; ++p) {
                        if (cd < hd[p]) {
                            float tf = hd[p]; hd[p] = cd; cd = tf;
                            tf = hl[p]; hl[p] = cl; cl = tf;
                            int ti = hi[p]; hi[p] = ci; ci = ti;
                        }
                    }
                }
            }
        }
        __syncthreads();
    }

    // selected probabilities
    float rsum = 0.f;
    if (t < RPB) {
        float inv = 1.f / s_run;
        #pragma unroll
        for (int j = 0; j < TOPK; ++j) {
            float p = __expf(hl[j] - m_run) * inv;
            sel_p[t][j] = p; sel_i[t][j] = hi[j];
            rsum += p;
        }
    }
    __syncthreads();

    // rep output: coalesced zero-fill then scatter 8 probs per row
    float* rep0 = out + 2 + (size_t)NELEM;   // out + 16777218 (8B-aligned)
    {
        float2* zb = (float2*)(rep0 + (size_t)n0 * KDIM);
        #pragma unroll 4
        for (int i = 0; i < 64; ++i) zb[(size_t)i * 256 + t] = make_float2(0.f, 0.f);
    }
    __syncthreads();
    if (t < RPB) {
        float* rr = rep0 + (size_t)(n0 + t) * KDIM;
        #pragma unroll
        for (int j = 0; j < TOPK; ++j) {
            rr[sel_i[t][j]] = sel_p[t][j];
            atomicAdd(&counts[sel_i[t][j]], 1);
        }
    }

    // recon = sum_j p_j * dict[idx_j], written flat (== .view(B,C,H,W));
    // fused MSE vs x in raw memory order
    float lsum = 0.f;
    {
        int r = t >> 3, tl = t & 7;
        int n = n0 + r;
        float acc[32];
        #pragma unroll
        for (int i = 0; i < 32; ++i) acc[i] = 0.f;
        #pragma unroll
        for (int j = 0; j < TOPK; ++j) {
            float p = sel_p[r][j];
            const float* dp = dict + (size_t)sel_i[r][j] * CDIM + tl * 32;
            #pragma unroll
            for (int i = 0; i < 32; i += 4) {
                float4 d4 = *(const float4*)(dp + i);
                acc[i]   += p * d4.x; acc[i+1] += p * d4.y;
                acc[i+2] += p * d4.z; acc[i+3] += p * d4.w;
            }
        }
        const float* xf = x + (size_t)n * CDIM + tl * 32;
        float* ro = out + 1 + (size_t)n * CDIM + tl * 32;
        #pragma unroll
        for (int i = 0; i < 32; i += 4) {
            float4 xv = *(const float4*)(xf + i);
            float e0 = xv.x - acc[i],   e1 = xv.y - acc[i+1];
            float e2 = xv.z - acc[i+2], e3 = xv.w - acc[i+3];
            lsum += e0*e0; lsum += e1*e1; lsum += e2*e2; lsum += e3*e3;
            ro[i] = acc[i]; ro[i+1] = acc[i+1]; ro[i+2] = acc[i+2]; ro[i+3] = acc[i+3];
        }
    }

    // block reduction of loss / regularization partials
    float v1 = lsum, v2 = rsum;
    #pragma unroll
    for (int off = 32; off; off >>= 1) {
        v1 += __shfl_down(v1, off);
        v2 += __shfl_down(v2, off);
    }
    if ((t & 63) == 0) { atomicAdd(loss_acc, v1); atomicAdd(reg_acc, v2); }
}

// ---------------------------------------------------------------- finalize
__global__ void dl_final(const float* __restrict__ loss_acc,
                         const float* __restrict__ reg_acc,
                         const int* __restrict__ counts,
                         float* __restrict__ out)
{
    __shared__ float red[4];
    int t = threadIdx.x;
    float e = 0.f;
    for (int k = t; k < KDIM; k += 256) {
        float p = (float)counts[k] * (1.0f / 524288.0f);  // counts/(8N), exact normalization
        e += p * logf(p + 1e-10f);
    }
    #pragma unroll
    for (int off = 32; off; off >>= 1) e += __shfl_down(e, off);
    if ((t & 63) == 0) red[t >> 6] = e;
    __syncthreads();
    if (t == 0) {
        float et = red[0] + red[1] + red[2] + red[3];
        out[(size_t)NELEM + 1] = __expf(-et);                       // perplexity
        out[0] = 2.0f * loss_acc[0] / (float)NELEM + reg_acc[0];    // recon_loss + regularization
    }
}

extern "C" void kernel_launch(void* const* d_in, const int* in_sizes, int n_in,
                              void* d_out, int out_size, void* d_ws, size_t ws_size,
                              hipStream_t stream) {
    const float* x    = (const float*)d_in[0];
    const float* dict = (const float*)d_in[1];
    const float* Wm   = (const float*)d_in[2];
    const float* bv   = (const float*)d_in[3];
    float* out = (float*)d_out;

    float* loss_acc = (float*)d_ws;
    float* reg_acc  = loss_acc + 1;
    int*   counts   = (int*)((char*)d_ws + 16);
    float* dn       = (float*)((char*)d_ws + 16 + 4096);

    hipMemsetAsync(d_ws, 0, 16 + 4096, stream);
    dl_norms<<<KDIM / 256, 256, 0, stream>>>(dict, dn);
    dl_main<<<NROWS / RPB, 256, 0, stream>>>(x, dict, Wm, bv, dn, out,
                                             loss_acc, reg_acc, counts);
    dl_final<<<1, 256, 0, stream>>>(loss_acc, reg_acc, counts, out);
}

// Round 2
// 820.805 us; speedup vs baseline: 3.7368x; 3.7368x over previous
//
#include <hip/hip_runtime.h>
#include <math.h>

#define CDIM 256
#define KDIM 1024
#define TOPK 8
#define MROWS 64
#define NELEM 16777216
#define LGST 131

typedef unsigned short u16;
typedef unsigned int u32;
typedef __attribute__((ext_vector_type(8))) short s16x8;
typedef __attribute__((ext_vector_type(8))) __bf16 b16x8;
typedef __attribute__((ext_vector_type(16))) float f32x16;

#define ZERO16 {0.f,0.f,0.f,0.f,0.f,0.f,0.f,0.f,0.f,0.f,0.f,0.f,0.f,0.f,0.f,0.f}

// ws layout (bytes)
#define WS_COUNTS 64
#define WS_DN     4608
#define WS_WH     16384
#define WS_DH     (WS_WH + 524288)
#define WS_DL     (WS_DH + 524288)

__device__ __forceinline__ u16 f2bf(float f) {
    u32 u = __builtin_bit_cast(u32, f);
    u += 0x7FFFu + ((u >> 16) & 1u);
    return (u16)(u >> 16);
}
__device__ __forceinline__ float bf2f(u16 h) {
    return __builtin_bit_cast(float, ((u32)h) << 16);
}
__device__ __forceinline__ f32x16 mfma16(s16x8 a, s16x8 b, f32x16 c) {
    return __builtin_amdgcn_mfma_f32_32x32x16_bf16(
        __builtin_bit_cast(b16x8, a), __builtin_bit_cast(b16x8, b), c, 0, 0, 0);
}

// compare-exchange on sorted-ascending (dist, idx) with logit payload
#define CE(A, B) { \
    bool sw_ = (hd[B] < hd[A]) || (hd[B] == hd[A] && hix[B] < hix[A]); \
    if (sw_) { float td_ = hd[A]; hd[A] = hd[B]; hd[B] = td_; \
               int ti_ = hix[A]; hix[A] = hix[B]; hix[B] = ti_; \
               float tl_ = hlg[A]; hlg[A] = hlg[B]; hlg[B] = tl_; } }

// ------------------------------------------------ prepass: bf16 splits + norms
__global__ __launch_bounds__(256)
void dl_prep(const float* __restrict__ Wm, const float* __restrict__ dict,
             u16* __restrict__ Wh, u16* __restrict__ Dh, u16* __restrict__ Dl,
             float* __restrict__ dn)
{
    __shared__ float red[4];
    const int k = blockIdx.x, c = threadIdx.x;
    const size_t idx = ((size_t)k << 8) + c;
    float w = Wm[idx];
    Wh[idx] = f2bf(w);
    float d = dict[idx];
    u16 dh = f2bf(d);
    Dh[idx] = dh;
    Dl[idx] = f2bf(d - bf2f(dh));
    float sq = d * d;
    #pragma unroll
    for (int off = 32; off; off >>= 1) sq += __shfl_down(sq, off);
    if ((c & 63) == 0) red[c >> 6] = sq;
    __syncthreads();
    if (c == 0) dn[k] = red[0] + red[1] + red[2] + red[3];
}

// ------------------------------------------------ main fused kernel
__global__ __launch_bounds__(512, 2)
void dl_main(const float* __restrict__ x, const float* __restrict__ dict,
             const float* __restrict__ bv, const u16* __restrict__ Wh,
             const u16* __restrict__ Dh, const u16* __restrict__ Dl,
             const float* __restrict__ dnp, float* __restrict__ out,
             float* __restrict__ loss_acc, float* __restrict__ reg_acc,
             int* __restrict__ counts)
{
    __shared__ u16 xh[MROWS][CDIM];     // bf16 hi of x rows (XOR-swizzled)
    __shared__ u16 xl[MROWS][CDIM];     // bf16 lo
    __shared__ float lg[MROWS][LGST];   // raw logit dots for chunk (128 cols)
    __shared__ float dd[MROWS][LGST];   // raw dict dots for chunk
    __shared__ float xnp[MROWS][8];
    __shared__ float b_s[128];
    __shared__ float dn_s[128];
    __shared__ float sel_p[MROWS][TOPK];
    __shared__ int   sel_i[MROWS][TOPK];

    const int t = threadIdx.x;
    const int lane = t & 63;
    const int wid = t >> 6;
    const int n0 = blockIdx.x * MROWS;

    // ---- phase 0: stage x -> bf16 hi/lo (swizzled) + row norms
    {
        const int r = t & 63, cs = t >> 6;
        const float* xb = x + ((size_t)(n0 >> 12) << 20) + (n0 & 4095) + r;
        float sq = 0.f;
        #pragma unroll 4
        for (int i = 0; i < 32; i += 2) {
            int c = cs * 32 + i;
            float g0 = xb[(size_t)c << 12];
            float g1 = xb[(size_t)(c + 1) << 12];
            sq += g0 * g0 + g1 * g1;
            u16 h0 = f2bf(g0), h1 = f2bf(g1);
            u16 e0 = f2bf(g0 - bf2f(h0)), e1 = f2bf(g1 - bf2f(h1));
            int byte = (r * 512 + c * 2) ^ ((r & 7) << 4);
            *(u32*)((char*)xh + byte) = (u32)h0 | ((u32)h1 << 16);
            *(u32*)((char*)xl + byte) = (u32)e0 | ((u32)e1 << 16);
        }
        xnp[r][cs] = sq;
    }
    __syncthreads();

    const int cr = t >> 3, cs8 = t & 7;   // consume: row, sub-thread
    float xn = 0.f;
    #pragma unroll
    for (int j = 0; j < 8; ++j) xn += xnp[cr][j];

    float m_run = -INFINITY, s_run = 0.f;
    float hd[TOPK], hlg[TOPK];
    int hix[TOPK];
    #pragma unroll
    for (int j = 0; j < TOPK; ++j) { hd[j] = INFINITY; hlg[j] = 0.f; hix[j] = 0; }

    const int ct = wid & 3, kh = wid >> 2;     // atom-tile, K-half
    const int arow = lane & 31, ag = lane >> 5;
    const int swz = (arow & 7) << 4;

    for (int ck = 0; ck < 8; ++ck) {
        // stage bias / dict-norms for this chunk's atoms
        if (t < 128) b_s[t] = bv[ck * 128 + t];
        else if (t < 256) dn_s[t - 128] = dnp[ck * 128 + (t - 128)];

        f32x16 accL0 = ZERO16, accL1 = ZERO16, accD0 = ZERO16, accD1 = ZERO16;
        const int a0 = ck * 128 + ct * 32;
        const u16* bbase = (const u16*)0;
        const size_t brow = ((size_t)(a0 + arow) << 8) + (size_t)(ag * 8);
        (void)bbase;

        #pragma unroll 2
        for (int kk = 0; kk < 8; ++kk) {
            const int kg = kh * 8 + kk;
            const int cof2 = kg * 32 + ag * 16;    // byte offset in row
            s16x8 bw  = *(const s16x8*)(Wh + brow + kg * 16);
            s16x8 bdh = *(const s16x8*)(Dh + brow + kg * 16);
            s16x8 bdl = *(const s16x8*)(Dl + brow + kg * 16);
            s16x8 a0h = *(const s16x8*)((const char*)xh + ((arow * 512 + cof2) ^ swz));
            s16x8 a1h = *(const s16x8*)((const char*)xh + (((arow + 32) * 512 + cof2) ^ swz));
            s16x8 a0l = *(const s16x8*)((const char*)xl + ((arow * 512 + cof2) ^ swz));
            s16x8 a1l = *(const s16x8*)((const char*)xl + (((arow + 32) * 512 + cof2) ^ swz));
            accL0 = mfma16(a0h, bw, accL0);
            accL1 = mfma16(a1h, bw, accL1);
            accD0 = mfma16(a0h, bdh, accD0);
            accD1 = mfma16(a1h, bdh, accD1);
            accD0 = mfma16(a0l, bdh, accD0);
            accD1 = mfma16(a1l, bdh, accD1);
            accD0 = mfma16(a0h, bdl, accD0);
            accD1 = mfma16(a1h, bdl, accD1);
        }

        const int col = ct * 32 + arow;
        const int rb = 4 * ag;
        if (kh == 0) {
            #pragma unroll
            for (int rg = 0; rg < 4; ++rg)
                #pragma unroll
                for (int q = 0; q < 4; ++q) {
                    int row = q + 8 * rg + rb;
                    lg[row][col]      = accL0[4 * rg + q];
                    lg[row + 32][col] = accL1[4 * rg + q];
                    dd[row][col]      = accD0[4 * rg + q];
                    dd[row + 32][col] = accD1[4 * rg + q];
                }
        }
        __syncthreads();
        if (kh == 1) {
            #pragma unroll
            for (int rg = 0; rg < 4; ++rg)
                #pragma unroll
                for (int q = 0; q < 4; ++q) {
                    int row = q + 8 * rg + rb;
                    lg[row][col]      += accL0[4 * rg + q];
                    lg[row + 32][col] += accL1[4 * rg + q];
                    dd[row][col]      += accD0[4 * rg + q];
                    dd[row + 32][col] += accD1[4 * rg + q];
                }
        }
        __syncthreads();

        // ---- consume: online softmax + top-8 (8 sub-threads per row)
        {
            float lv[16];
            #pragma unroll
            for (int j = 0; j < 16; ++j)
                lv[j] = lg[cr][cs8 * 16 + j] + b_s[cs8 * 16 + j];
            float mx = m_run;
            #pragma unroll
            for (int j = 0; j < 16; ++j) mx = fmaxf(mx, lv[j]);
            s_run *= __expf(m_run - mx);
            #pragma unroll
            for (int j = 0; j < 16; ++j) s_run += __expf(lv[j] - mx);
            m_run = mx;
            #pragma unroll
            for (int j = 0; j < 16; ++j) {
                int cloc = cs8 * 16 + j;
                float dv = xn + dn_s[cloc] - 2.f * dd[cr][cloc];
                if (dv < hd[TOPK - 1]) {
                    float cd = dv, cl = lv[j];
                    int ci = ck * 128 + cloc;
                    #pragma unroll
                    for (int p = 0; p < TOPK; ++p) {
                        bool lt = cd < hd[p];
                        float td = hd[p]; int ti = hix[p]; float tl2 = hlg[p];
                        if (lt) { hd[p] = cd; hix[p] = ci; hlg[p] = cl;
                                  cd = td; ci = ti; cl = tl2; }
                    }
                }
            }
        }
        __syncthreads();
    }

    // ---- merge softmax state across the 8 sub-threads of each row
    #pragma unroll
    for (int k = 1; k <= 4; k <<= 1) {
        float mo = __shfl_xor(m_run, k);
        float so = __shfl_xor(s_run, k);
        float mn = fmaxf(m_run, mo);
        s_run = s_run * __expf(m_run - mn) + so * __expf(mo - mn);
        m_run = mn;
    }
    // ---- merge top-8 lists (bitonic) across the 8 sub-threads
    #pragma unroll
    for (int k = 1; k <= 4; k <<= 1) {
        float od[TOPK], ol[TOPK]; int oi[TOPK];
        #pragma unroll
        for (int j = 0; j < TOPK; ++j) {
            od[j] = __shfl_xor(hd[j], k);
            ol[j] = __shfl_xor(hlg[j], k);
            oi[j] = __shfl_xor(hix[j], k);
        }
        #pragma unroll
        for (int j = 0; j < TOPK; ++j) {
            float bd2 = od[7 - j]; int bi2 = oi[7 - j]; float bl2 = ol[7 - j];
            if (bd2 < hd[j] || (bd2 == hd[j] && bi2 < hix[j])) {
                hd[j] = bd2; hix[j] = bi2; hlg[j] = bl2;
            }
        }
        CE(0,4) CE(1,5) CE(2,6) CE(3,7)
        CE(0,2) CE(1,3) CE(4,6) CE(5,7)
        CE(0,1) CE(2,3) CE(4,5) CE(6,7)
    }

    // ---- selected probabilities, counts, regularization
    float rsum = 0.f;
    if (cs8 == 0) {
        float inv = 1.f / s_run;
        #pragma unroll
        for (int j = 0; j < TOPK; ++j) {
            float p = __expf(hlg[j] - m_run) * inv;
            sel_p[cr][j] = p;
            sel_i[cr][j] = hix[j];
            rsum += p;
            atomicAdd(&counts[hix[j]], 1);
        }
    }
    {
        float v2 = rsum;
        #pragma unroll
        for (int off = 32; off; off >>= 1) v2 += __shfl_down(v2, off);
        if (lane == 0) atomicAdd(reg_acc, v2);
    }
    __syncthreads();

    // ---- rep: zero-fill then scatter
    float* rep0 = out + 2 + (size_t)NELEM;
    {
        float2* zb = (float2*)(rep0 + ((size_t)n0 << 10));
        #pragma unroll 8
        for (int i = 0; i < 64; ++i) zb[i * 512 + t] = make_float2(0.f, 0.f);
    }
    __syncthreads();
    {
        int rr = t >> 3, j = t & 7;
        rep0[((size_t)(n0 + rr) << 10) + sel_i[rr][j]] = sel_p[rr][j];
    }

    // ---- recon (flat .view semantics) + fused MSE vs x (x = hi+lo from LDS)
    float lsum = 0.f;
    {
        int rr = t >> 3, tl = t & 7;
        int n = n0 + rr;
        float acc[32];
        #pragma unroll
        for (int i = 0; i < 32; ++i) acc[i] = 0.f;
        #pragma unroll
        for (int j = 0; j < TOPK; ++j) {
            float p = sel_p[rr][j];
            const float* dp = dict + ((size_t)sel_i[rr][j] << 8) + tl * 32;
            #pragma unroll
            for (int i = 0; i < 32; i += 4) {
                float4 d4 = *(const float4*)(dp + i);
                acc[i]     += p * d4.x; acc[i + 1] += p * d4.y;
                acc[i + 2] += p * d4.z; acc[i + 3] += p * d4.w;
            }
        }
        float* ro = out + 1 + ((size_t)n << 8) + tl * 32;
        int swr = (rr & 7) << 4;
        #pragma unroll
        for (int i = 0; i < 32; i += 2) {
            int c = tl * 32 + i;
            int byte = (rr * 512 + c * 2) ^ swr;
            u32 ph = *(const u32*)((const char*)xh + byte);
            u32 pl = *(const u32*)((const char*)xl + byte);
            float xv0 = bf2f((u16)ph) + bf2f((u16)pl);
            float xv1 = bf2f((u16)(ph >> 16)) + bf2f((u16)(pl >> 16));
            float e0 = xv0 - acc[i], e1 = xv1 - acc[i + 1];
            lsum += e0 * e0 + e1 * e1;
            ro[i] = acc[i]; ro[i + 1] = acc[i + 1];
        }
    }
    {
        #pragma unroll
        for (int off = 32; off; off >>= 1) lsum += __shfl_down(lsum, off);
        if (lane == 0) atomicAdd(loss_acc, lsum);
    }
}

// ------------------------------------------------ finalize scalars
__global__ void dl_final(const float* __restrict__ loss_acc,
                         const float* __restrict__ reg_acc,
                         const int* __restrict__ counts,
                         float* __restrict__ out)
{
    __shared__ float red[4];
    int t = threadIdx.x;
    float e = 0.f;
    for (int k = t; k < KDIM; k += 256) {
        float p = (float)counts[k] * (1.0f / 524288.0f);
        e += p * logf(p + 1e-10f);
    }
    #pragma unroll
    for (int off = 32; off; off >>= 1) e += __shfl_down(e, off);
    if ((t & 63) == 0) red[t >> 6] = e;
    __syncthreads();
    if (t == 0) {
        float et = red[0] + red[1] + red[2] + red[3];
        out[(size_t)NELEM + 1] = __expf(-et);                     // perplexity
        out[0] = 2.0f * loss_acc[0] / (float)NELEM + reg_acc[0];  // loss + reg
    }
}

extern "C" void kernel_launch(void* const* d_in, const int* in_sizes, int n_in,
                              void* d_out, int out_size, void* d_ws, size_t ws_size,
                              hipStream_t stream) {
    const float* x    = (const float*)d_in[0];
    const float* dict = (const float*)d_in[1];
    const float* Wm   = (const float*)d_in[2];
    const float* bv   = (const float*)d_in[3];
    float* out = (float*)d_out;

    float* loss_acc = (float*)d_ws;
    float* reg_acc  = loss_acc + 1;
    int*   counts   = (int*)((char*)d_ws + WS_COUNTS);
    float* dn       = (float*)((char*)d_ws + WS_DN);
    u16*   Wh       = (u16*)((char*)d_ws + WS_WH);
    u16*   Dh       = (u16*)((char*)d_ws + WS_DH);
    u16*   Dl       = (u16*)((char*)d_ws + WS_DL);

    hipMemsetAsync(d_ws, 0, 4608, stream);
    dl_prep<<<KDIM, 256, 0, stream>>>(Wm, dict, Wh, Dh, Dl, dn);
    dl_main<<<65536 / MROWS, 512, 0, stream>>>(x, dict, bv, Wh, Dh, Dl, dn, out,
                                               loss_acc, reg_acc, counts);
    dl_final<<<1, 256, 0, stream>>>(loss_acc, reg_acc, counts, out);
}

// Round 3
// 635.102 us; speedup vs baseline: 4.8294x; 1.2924x over previous
//
#include <hip/hip_runtime.h>
#include <math.h>

#define CDIM 256
#define KDIM 1024
#define TOPK 8
#define MROWS 64
#define NELEM 16777216

typedef unsigned short u16;
typedef unsigned int u32;
typedef __attribute__((ext_vector_type(8))) short s16x8;
typedef __attribute__((ext_vector_type(8))) __bf16 b16x8;
typedef __attribute__((ext_vector_type(16))) float f32x16;

#define ZERO16 {0.f,0.f,0.f,0.f,0.f,0.f,0.f,0.f,0.f,0.f,0.f,0.f,0.f,0.f,0.f,0.f}

// ws layout (bytes)
#define WS_COUNTS 64
#define WS_DN     4608
#define WS_WH     16384
#define WS_DH     (WS_WH + 524288)
#define WS_DL     (WS_DH + 524288)

// smem layout (bytes)
#define SM_XH   0
#define SM_XL   32768
#define SM_B    65536
#define SM_DNS  69632
#define SM_XNP  73728
#define SM_TOT  75776
// merge overlay (over dead x-tile, after main loop)
#define SM_PD   0
#define SM_PI   4096
#define SM_PL   8192
#define SM_PM   12288
#define SM_PS   12800
#define SM_SELP 16384
#define SM_SELI 18432

__device__ __forceinline__ u16 f2bf(float f) {
    u32 u = __builtin_bit_cast(u32, f);
    u += 0x7FFFu + ((u >> 16) & 1u);
    return (u16)(u >> 16);
}
__device__ __forceinline__ float bf2f(u16 h) {
    return __builtin_bit_cast(float, ((u32)h) << 16);
}
__device__ __forceinline__ f32x16 mfma16(s16x8 a, s16x8 b, f32x16 c) {
    return __builtin_amdgcn_mfma_f32_32x32x16_bf16(
        __builtin_bit_cast(b16x8, a), __builtin_bit_cast(b16x8, b), c, 0, 0, 0);
}

#define CE(A, B) { \
    bool sw_ = (hd[B] < hd[A]) || (hd[B] == hd[A] && hix[B] < hix[A]); \
    if (sw_) { float td_ = hd[A]; hd[A] = hd[B]; hd[B] = td_; \
               int ti_ = hix[A]; hix[A] = hix[B]; hix[B] = ti_; \
               float tl_ = hlg[A]; hlg[A] = hlg[B]; hlg[B] = tl_; } }

#define INS(DV, LV, CI) \
    if ((DV) < hd[7]) { float cd_ = (DV), cl_ = (LV); int ci_ = (CI); \
        _Pragma("unroll") \
        for (int p_ = 0; p_ < 8; ++p_) { bool lt_ = cd_ < hd[p_]; \
            float td_ = hd[p_]; int ti_ = hix[p_]; float tp_ = hlg[p_]; \
            if (lt_) { hd[p_] = cd_; hix[p_] = ci_; hlg[p_] = cl_; \
                       cd_ = td_; ci_ = ti_; cl_ = tp_; } } }

// merge sorted 8-list in od/oi/ol into hd/hix/hlg (both sorted ascending)
#define MERGE8() { \
    _Pragma("unroll") \
    for (int j_ = 0; j_ < 8; ++j_) { \
        float bd_ = od[7 - j_]; int bi_ = oi[7 - j_]; float bl_ = ol[7 - j_]; \
        if (bd_ < hd[j_] || (bd_ == hd[j_] && bi_ < hix[j_])) { \
            hd[j_] = bd_; hix[j_] = bi_; hlg[j_] = bl_; } } \
    CE(0,4) CE(1,5) CE(2,6) CE(3,7) \
    CE(0,2) CE(1,3) CE(4,6) CE(5,7) \
    CE(0,1) CE(2,3) CE(4,5) CE(6,7) }

// ------------------------------------------------ prepass: bf16 splits + norms
__global__ __launch_bounds__(256)
void dl_prep(const float* __restrict__ Wm, const float* __restrict__ dict,
             u16* __restrict__ Wh, u16* __restrict__ Dh, u16* __restrict__ Dl,
             float* __restrict__ dn)
{
    __shared__ float red[4];
    const int k = blockIdx.x, c = threadIdx.x;
    const size_t idx = ((size_t)k << 8) + c;
    float w = Wm[idx];
    Wh[idx] = f2bf(w);
    float d = dict[idx];
    u16 dh = f2bf(d);
    Dh[idx] = dh;
    Dl[idx] = f2bf(d - bf2f(dh));
    float sq = d * d;
    #pragma unroll
    for (int off = 32; off; off >>= 1) sq += __shfl_down(sq, off);
    if ((c & 63) == 0) red[c >> 6] = sq;
    __syncthreads();
    if (c == 0) dn[k] = red[0] + red[1] + red[2] + red[3];
}

// ------------------------------------------------ main fused kernel
__global__ __launch_bounds__(512, 4)
void dl_main(const float* __restrict__ x, const float* __restrict__ dict,
             const float* __restrict__ bv, const u16* __restrict__ Wh,
             const u16* __restrict__ Dh, const u16* __restrict__ Dl,
             const float* __restrict__ dnp, float* __restrict__ out,
             float* __restrict__ loss_acc, float* __restrict__ reg_acc,
             int* __restrict__ counts)
{
    __shared__ __align__(16) char smem[SM_TOT];
    u16*   xh   = (u16*)(smem + SM_XH);
    u16*   xl   = (u16*)(smem + SM_XL);
    float* b_s  = (float*)(smem + SM_B);
    float* dn_s = (float*)(smem + SM_DNS);
    float* xnp  = (float*)(smem + SM_XNP);

    const int t = threadIdx.x;
    const int lane = t & 63;
    const int wid = t >> 6;
    const int n0 = blockIdx.x * MROWS;

    // ---- phase 0: stage x -> bf16 hi/lo (swizzled) + row-norm partials + b/dn
    {
        const int r = t & 63, cs = t >> 6;
        const float* xb = x + ((size_t)(n0 >> 12) << 20) + (n0 & 4095) + r;
        float sq = 0.f;
        #pragma unroll 4
        for (int i = 0; i < 32; i += 2) {
            int c = cs * 32 + i;
            float g0 = xb[(size_t)c << 12];
            float g1 = xb[(size_t)(c + 1) << 12];
            sq += g0 * g0 + g1 * g1;
            u16 h0 = f2bf(g0), h1 = f2bf(g1);
            u16 e0 = f2bf(g0 - bf2f(h0)), e1 = f2bf(g1 - bf2f(h1));
            int byte = (r * 512 + c * 2) ^ ((r & 7) << 4);
            *(u32*)((char*)xh + byte) = (u32)h0 | ((u32)h1 << 16);
            *(u32*)((char*)xl + byte) = (u32)e0 | ((u32)e1 << 16);
        }
        xnp[r * 8 + cs] = sq;
        b_s[t] = bv[t];  b_s[512 + t] = bv[512 + t];
        dn_s[t] = dnp[t]; dn_s[512 + t] = dnp[512 + t];
    }
    __syncthreads();

    // ---- rep zero-fill early: overlaps HBM writes with compute
    float* rep0 = out + 2 + (size_t)NELEM;
    {
        float2* zb = (float2*)(rep0 + ((size_t)n0 << 10));
        #pragma unroll 8
        for (int i = 0; i < 64; ++i) zb[i * 512 + t] = make_float2(0.f, 0.f);
    }

    const int arow = lane & 31, hl = lane >> 5;
    const int rgrp = wid & 1, agrp = wid >> 1;
    const int xrow = rgrp * 32 + arow;
    const int swz = (arow & 7) << 4;

    // row norm for this lane's x-row
    float xn = 0.f;
    {
        const float* xp = xnp + xrow * 8;
        #pragma unroll
        for (int j = 0; j < 8; ++j) xn += xp[j];
    }

    float m_run = -INFINITY, s_run = 0.f;
    float hd[TOPK], hlg[TOPK];
    int hix[TOPK];
    #pragma unroll
    for (int j = 0; j < TOPK; ++j) { hd[j] = INFINITY; hlg[j] = 0.f; hix[j] = 0; }

    // ---- barrier-free main loop: 8 chunks of 128 atoms
    #pragma unroll 1
    for (int ck = 0; ck < 8; ++ck) {
        const size_t arow_g = (size_t)(ck * 128 + agrp * 32 + arow);
        const u16* Wp  = Wh + (arow_g << 8) + hl * 8;
        const u16* Dhp = Dh + (arow_g << 8) + hl * 8;
        const u16* Dlp = Dl + (arow_g << 8) + hl * 8;

        f32x16 accL = ZERO16, accD = ZERO16;
        #pragma unroll 2
        for (int kst = 0; kst < 16; ++kst) {
            int boff = (xrow * 512 + hl * 16 + kst * 32) ^ swz;
            s16x8 aw  = *(const s16x8*)(Wp  + kst * 16);
            s16x8 adh = *(const s16x8*)(Dhp + kst * 16);
            s16x8 adl = *(const s16x8*)(Dlp + kst * 16);
            s16x8 bh = *(const s16x8*)((const char*)xh + boff);
            s16x8 bl = *(const s16x8*)((const char*)xl + boff);
            accL = mfma16(aw,  bh, accL);   // logits (hi only)
            accD = mfma16(adh, bh, accD);   // x_hi . d_hi
            accD = mfma16(adh, bl, accD);   // x_lo . d_hi
            accD = mfma16(adl, bh, accD);   // x_hi . d_lo
        }

        // consume: lane-local online softmax + top-8 (16 atoms per lane)
        #pragma unroll
        for (int rg = 0; rg < 4; ++rg) {
            const int mb = ck * 128 + agrp * 32 + 8 * rg + 4 * hl;
            float4 b4 = *(const float4*)(b_s + mb);
            float4 n4 = *(const float4*)(dn_s + mb);
            float lv0 = accL[4*rg+0] + b4.x, lv1 = accL[4*rg+1] + b4.y;
            float lv2 = accL[4*rg+2] + b4.z, lv3 = accL[4*rg+3] + b4.w;
            float mx = fmaxf(fmaxf(fmaxf(lv0, lv1), fmaxf(lv2, lv3)), m_run);
            s_run = s_run * __expf(m_run - mx)
                  + __expf(lv0 - mx) + __expf(lv1 - mx)
                  + __expf(lv2 - mx) + __expf(lv3 - mx);
            m_run = mx;
            float dv0 = xn + n4.x - 2.f * accD[4*rg+0];
            float dv1 = xn + n4.y - 2.f * accD[4*rg+1];
            float dv2 = xn + n4.z - 2.f * accD[4*rg+2];
            float dv3 = xn + n4.w - 2.f * accD[4*rg+3];
            INS(dv0, lv0, mb + 0)
            INS(dv1, lv1, mb + 1)
            INS(dv2, lv2, mb + 2)
            INS(dv3, lv3, mb + 3)
        }
    }

    // ---- merge the two atom-halves (lane n <-> lane n+32): same x-row
    {
        float mo = __shfl_xor(m_run, 32);
        float so = __shfl_xor(s_run, 32);
        float mn = fmaxf(m_run, mo);
        s_run = s_run * __expf(m_run - mn) + so * __expf(mo - mn);
        m_run = mn;
        float od[TOPK], ol[TOPK]; int oi[TOPK];
        #pragma unroll
        for (int j = 0; j < TOPK; ++j) {
            od[j] = __shfl_xor(hd[j], 32);
            ol[j] = __shfl_xor(hlg[j], 32);
            oi[j] = __shfl_xor(hix[j], 32);
        }
        MERGE8()
    }

    // ---- cross-wave merge (4 atom-groups -> 1), overlaid on dead x-tile
    float* pd = (float*)(smem + SM_PD);
    int*   pi = (int*)(smem + SM_PI);
    float* pl = (float*)(smem + SM_PL);
    float* pm = (float*)(smem + SM_PM);
    float* ps = (float*)(smem + SM_PS);
    float* selp = (float*)(smem + SM_SELP);
    int*   seli = (int*)(smem + SM_SELI);

    __syncthreads();   // x-tile reads done; zero-fill stores drained
    if (wid >= 4 && lane < 32) {            // agrp 2,3 publish
        int base = ((agrp - 2) * 64 + xrow);
        #pragma unroll
        for (int j = 0; j < TOPK; ++j) {
            pd[base * 8 + j] = hd[j]; pi[base * 8 + j] = hix[j]; pl[base * 8 + j] = hlg[j];
        }
        pm[base] = m_run; ps[base] = s_run;
    }
    __syncthreads();
    if (wid < 4 && lane < 32) {             // agrp 0,1 absorb agrp 2,3
        int base = (agrp * 64 + xrow);
        float od[TOPK], ol[TOPK]; int oi[TOPK];
        #pragma unroll
        for (int j = 0; j < TOPK; ++j) {
            od[j] = pd[base * 8 + j]; oi[j] = pi[base * 8 + j]; ol[j] = pl[base * 8 + j];
        }
        float mo = pm[base], so = ps[base];
        float mn = fmaxf(m_run, mo);
        s_run = s_run * __expf(m_run - mn) + so * __expf(mo - mn);
        m_run = mn;
        MERGE8()
    }
    __syncthreads();
    if ((wid == 2 || wid == 3) && lane < 32) {   // agrp1 publish
        #pragma unroll
        for (int j = 0; j < TOPK; ++j) {
            pd[xrow * 8 + j] = hd[j]; pi[xrow * 8 + j] = hix[j]; pl[xrow * 8 + j] = hlg[j];
        }
        pm[xrow] = m_run; ps[xrow] = s_run;
    }
    __syncthreads();
    float rsum = 0.f;
    if (wid < 2 && lane < 32) {                  // agrp0 final merge + select
        float od[TOPK], ol[TOPK]; int oi[TOPK];
        #pragma unroll
        for (int j = 0; j < TOPK; ++j) {
            od[j] = pd[xrow * 8 + j]; oi[j] = pi[xrow * 8 + j]; ol[j] = pl[xrow * 8 + j];
        }
        float mo = pm[xrow], so = ps[xrow];
        float mn = fmaxf(m_run, mo);
        s_run = s_run * __expf(m_run - mn) + so * __expf(mo - mn);
        m_run = mn;
        MERGE8()
        float inv = 1.f / s_run;
        #pragma unroll
        for (int j = 0; j < TOPK; ++j) {
            float p = __expf(hlg[j] - m_run) * inv;
            selp[xrow * 8 + j] = p;
            seli[xrow * 8 + j] = hix[j];
            rsum += p;
            atomicAdd(&counts[hix[j]], 1);
        }
    }
    {   // regularization partial
        float v2 = rsum;
        #pragma unroll
        for (int off = 32; off; off >>= 1) v2 += __shfl_down(v2, off);
        if (lane == 0) atomicAdd(reg_acc, v2);
    }
    __syncthreads();

    // ---- rep scatter (zeros already written + drained at first merge barrier)
    {
        int rr = t >> 3, j = t & 7;
        rep0[((size_t)(n0 + rr) << 10) + seli[rr * 8 + j]] = selp[rr * 8 + j];
    }

    // ---- recon (flat .view semantics) + fused MSE vs x in flat memory order
    float lsum = 0.f;
    {
        int rr = t >> 3, tl = t & 7;
        size_t n = (size_t)(n0 + rr);
        float acc[32];
        #pragma unroll
        for (int i = 0; i < 32; ++i) acc[i] = 0.f;
        #pragma unroll
        for (int j = 0; j < TOPK; ++j) {
            float p = selp[rr * 8 + j];
            const float* dp = dict + ((size_t)seli[rr * 8 + j] << 8) + tl * 32;
            #pragma unroll
            for (int i = 0; i < 32; i += 4) {
                float4 d4 = *(const float4*)(dp + i);
                acc[i]     += p * d4.x; acc[i + 1] += p * d4.y;
                acc[i + 2] += p * d4.z; acc[i + 3] += p * d4.w;
            }
        }
        const float* xf = x + (n << 8) + tl * 32;   // flat-order read, coalesced
        float* ro = out + 1 + (n << 8) + tl * 32;
        #pragma unroll
        for (int i = 0; i < 32; i += 4) {
            float4 xv = *(const float4*)(xf + i);
            float e0 = xv.x - acc[i],     e1 = xv.y - acc[i + 1];
            float e2 = xv.z - acc[i + 2], e3 = xv.w - acc[i + 3];
            lsum += e0 * e0 + e1 * e1 + e2 * e2 + e3 * e3;
            ro[i] = acc[i]; ro[i + 1] = acc[i + 1];
            ro[i + 2] = acc[i + 2]; ro[i + 3] = acc[i + 3];
        }
    }
    {
        #pragma unroll
        for (int off = 32; off; off >>= 1) lsum += __shfl_down(lsum, off);
        if (lane == 0) atomicAdd(loss_acc, lsum);
    }
}

// ------------------------------------------------ finalize scalars
__global__ void dl_final(const float* __restrict__ loss_acc,
                         const float* __restrict__ reg_acc,
                         const int* __restrict__ counts,
                         float* __restrict__ out)
{
    __shared__ float red[4];
    int t = threadIdx.x;
    float e = 0.f;
    for (int k = t; k < KDIM; k += 256) {
        float p = (float)counts[k] * (1.0f / 524288.0f);
        e += p * logf(p + 1e-10f);
    }
    #pragma unroll
    for (int off = 32; off; off >>= 1) e += __shfl_down(e, off);
    if ((t & 63) == 0) red[t >> 6] = e;
    __syncthreads();
    if (t == 0) {
        float et = red[0] + red[1] + red[2] + red[3];
        out[(size_t)NELEM + 1] = __expf(-et);                     // perplexity
        out[0] = 2.0f * loss_acc[0] / (float)NELEM + reg_acc[0];  // loss + reg
    }
}

extern "C" void kernel_launch(void* const* d_in, const int* in_sizes, int n_in,
                              void* d_out, int out_size, void* d_ws, size_t ws_size,
                              hipStream_t stream) {
    const float* x    = (const float*)d_in[0];
    const float* dict = (const float*)d_in[1];
    const float* Wm   = (const float*)d_in[2];
    const float* bv   = (const float*)d_in[3];
    float* out = (float*)d_out;

    float* loss_acc = (float*)d_ws;
    float* reg_acc  = loss_acc + 1;
    int*   counts   = (int*)((char*)d_ws + WS_COUNTS);
    float* dn       = (float*)((char*)d_ws + WS_DN);
    u16*   Wh       = (u16*)((char*)d_ws + WS_WH);
    u16*   Dh       = (u16*)((char*)d_ws + WS_DH);
    u16*   Dl       = (u16*)((char*)d_ws + WS_DL);

    hipMemsetAsync(d_ws, 0, 4608, stream);
    dl_prep<<<KDIM, 256, 0, stream>>>(Wm, dict, Wh, Dh, Dl, dn);
    dl_main<<<65536 / MROWS, 512, 0, stream>>>(x, dict, bv, Wh, Dh, Dl, dn, out,
                                               loss_acc, reg_acc, counts);
    dl_final<<<1, 256, 0, stream>>>(loss_acc, reg_acc, counts, out);
}